// Round 1
// baseline (219.975 us; speedup 1.0000x reference)
//
#include <hip/hip_runtime.h>

typedef __bf16 bf16x8 __attribute__((ext_vector_type(8)));
typedef float f32x4 __attribute__((ext_vector_type(4)));
typedef float fl4 __attribute__((ext_vector_type(4)));
typedef unsigned short us4 __attribute__((ext_vector_type(4)));
typedef unsigned short us8 __attribute__((ext_vector_type(8)));

__device__ __forceinline__ unsigned short f2bf(float f) {
  unsigned u = __builtin_bit_cast(unsigned, f);
  u += 0x7fffu + ((u >> 16) & 1u);
  return (unsigned short)(u >> 16);
}
__device__ __forceinline__ float bf2f(unsigned short h) {
  unsigned u = ((unsigned)h) << 16;
  return __builtin_bit_cast(float, u);
}

__device__ __forceinline__ void async16(const void* g, void* l) {
  __builtin_amdgcn_global_load_lds(
      (const __attribute__((address_space(1))) unsigned int*)g,
      (__attribute__((address_space(3))) unsigned int*)l, 16, 0, 0);
}

// ---------------- fp32 -> bf16 convert ----------------
__global__ __launch_bounds__(256) void cvt_bf16(const float* __restrict__ s,
                                                unsigned short* __restrict__ d, int n4) {
  int i = blockIdx.x * 256 + threadIdx.x;
  if (i >= n4) return;
  fl4 f = ((const fl4*)s)[i];
  us4 o;
  o[0] = f2bf(f[0]); o[1] = f2bf(f[1]); o[2] = f2bf(f[2]); o[3] = f2bf(f[3]);
  ((us4*)d)[i] = o;
}

// ---------------- transpose v: vT[b][c][t] = kqv[b*2048+t][2048+c] ----------------
__global__ __launch_bounds__(256) void transpose_v(const unsigned short* __restrict__ kqv,
                                                   unsigned short* __restrict__ vT) {
  int b = blockIdx.z;
  int t0 = blockIdx.x * 64;
  int c0 = blockIdx.y * 64;
  __shared__ unsigned short tile[64][68];
  int tid = threadIdx.x;
#pragma unroll
  for (int i = 0; i < 4; ++i) {
    int idx = i * 256 + tid;          // 0..1023
    int r = idx >> 4;                 // t row 0..63
    int c4 = (idx & 15) * 4;          // col group
    const unsigned short* src = kqv + ((size_t)(b * 2048 + t0 + r)) * 3072 + 2048 + c0 + c4;
    us4 v = *(const us4*)src;
    *(us4*)&tile[r][c4] = v;
  }
  __syncthreads();
#pragma unroll
  for (int i = 0; i < 4; ++i) {
    int idx = i * 256 + tid;
    int rc = idx >> 4;                // c row 0..63
    int t4 = (idx & 15) * 4;
    us4 v;
    v[0] = tile[t4 + 0][rc]; v[1] = tile[t4 + 1][rc];
    v[2] = tile[t4 + 2][rc]; v[3] = tile[t4 + 3][rc];
    unsigned short* dst = vT + ((size_t)(b * 1024 + c0 + rc)) * 2048 + t0 + t4;
    *(us4*)dst = v;
  }
}

// ---------------- B^T-format bf16 MFMA GEMM, 128x128 tile, 4 waves ----------------
// EPI 0: kqv out bf16 + bias. EPI 1: scores out bf16 * scale, skip blocks above diag.
// EPI 2: PV out fp32, K-loop truncated at diagonal.
#define BK 32

template <int EPI>
__global__ __launch_bounds__(256) void gemm_bt(
    const unsigned short* __restrict__ A, int lda, long long sA,
    const unsigned short* __restrict__ B, int ldb, long long sB,
    void* __restrict__ Cv, int ldc, long long sC,
    const float* __restrict__ bias, float scale, int K) {
  int bx = blockIdx.x, by = blockIdx.y, bz = blockIdx.z;
  if (EPI == 1 && bx > by) return;   // fully-masked causal block
  A += (size_t)bz * sA;
  B += (size_t)bz * sB;
  const int rowBase = by * 128;
  const int colBase = bx * 128;
  const int nk = (EPI == 2) ? (rowBase + 128) / BK : K / BK;

  __shared__ __align__(16) unsigned char lds[16384];  // A tile 8KB | B tile 8KB
  const int tid = threadIdx.x;
  const int lane = tid & 63;
  const int wid = tid >> 6;
  const int wr = (wid >> 1) * 64;
  const int wc = (wid & 1) * 64;

  f32x4 acc[4][4] = {};

  for (int kt = 0; kt < nk; ++kt) {
    __syncthreads();
    const int kof = kt * BK;
#pragma unroll
    for (int i = 0; i < 2; ++i) {
      int off = (i * 256 + tid) * 16;     // byte offset in 8KB tile
      int r = off >> 6;                   // tile row (64B = 32 bf16 per row)
      int gblk = ((off >> 4) & 3) ^ ((r >> 1) & 3);   // pre-swizzled source block
      async16(A + (size_t)(rowBase + r) * lda + kof + gblk * 8, lds + off);
      async16(B + (size_t)(colBase + r) * ldb + kof + gblk * 8, lds + 8192 + off);
    }
    __syncthreads();

    bf16x8 af[4], bfr[4];
#pragma unroll
    for (int m = 0; m < 4; ++m) {
      int row = wr + m * 16 + (lane & 15);
      int addr = row * 64 + ((((lane >> 4) ^ (row >> 1)) & 3) * 16);
      af[m] = *(const bf16x8*)(lds + addr);
    }
#pragma unroll
    for (int n = 0; n < 4; ++n) {
      int row = wc + n * 16 + (lane & 15);
      int addr = row * 64 + ((((lane >> 4) ^ (row >> 1)) & 3) * 16);
      bfr[n] = *(const bf16x8*)(lds + 8192 + addr);
    }
#pragma unroll
    for (int m = 0; m < 4; ++m)
#pragma unroll
      for (int n = 0; n < 4; ++n)
        acc[m][n] = __builtin_amdgcn_mfma_f32_16x16x32_bf16(af[m], bfr[n], acc[m][n], 0, 0, 0);
  }

  const int cr = (lane >> 4) * 4;
  const int cc = lane & 15;
  if constexpr (EPI == 0) {
    unsigned short* C = (unsigned short*)Cv;
#pragma unroll
    for (int n = 0; n < 4; ++n) {
      float bv = bias[colBase + wc + n * 16 + cc];
      int col = colBase + wc + n * 16 + cc;
#pragma unroll
      for (int m = 0; m < 4; ++m) {
        int row = rowBase + wr + m * 16 + cr;
#pragma unroll
        for (int i = 0; i < 4; ++i)
          C[(size_t)(row + i) * ldc + col] = f2bf(acc[m][n][i] + bv);
      }
    }
  } else if constexpr (EPI == 1) {
    unsigned short* C = (unsigned short*)Cv + (size_t)bz * sC;
#pragma unroll
    for (int n = 0; n < 4; ++n) {
      int col = colBase + wc + n * 16 + cc;
#pragma unroll
      for (int m = 0; m < 4; ++m) {
        int row = rowBase + wr + m * 16 + cr;
#pragma unroll
        for (int i = 0; i < 4; ++i)
          C[(size_t)(row + i) * ldc + col] = f2bf(acc[m][n][i] * scale);
      }
    }
  } else {
    float* C = (float*)Cv + (size_t)bz * sC;
#pragma unroll
    for (int n = 0; n < 4; ++n) {
      int col = colBase + wc + n * 16 + cc;
#pragma unroll
      for (int m = 0; m < 4; ++m) {
        int row = rowBase + wr + m * 16 + cr;
#pragma unroll
        for (int i = 0; i < 4; ++i)
          C[(size_t)(row + i) * ldc + col] = acc[m][n][i];
      }
    }
  }
}

// ---------------- causal softmax over S rows (in place, bf16) ----------------
// S was stored as (k.q) * (log2e/32): use exp2.
__global__ __launch_bounds__(256) void softmax_causal(unsigned short* __restrict__ S) {
  const int T = 2048;
  int t = blockIdx.x, b = blockIdx.y;
  unsigned short* row = S + ((size_t)b * T + t) * T;
  const int nv = t + 1;
  int tid = threadIdx.x;
  int lane = tid & 63, wid = tid >> 6;
  int s0 = tid * 8;
  us8 raw = *(const us8*)(row + s0);
  float v[8];
  float m = -3.0e38f;
#pragma unroll
  for (int j = 0; j < 8; ++j) {
    v[j] = bf2f(raw[j]);
    if (s0 + j < nv) m = fmaxf(m, v[j]);
  }
#pragma unroll
  for (int o = 32; o > 0; o >>= 1) m = fmaxf(m, __shfl_xor(m, o, 64));
  __shared__ float red[4];
  if (lane == 0) red[wid] = m;
  __syncthreads();
  m = fmaxf(fmaxf(red[0], red[1]), fmaxf(red[2], red[3]));
  __syncthreads();
  float sum = 0.f;
#pragma unroll
  for (int j = 0; j < 8; ++j) {
    float e = (s0 + j < nv) ? exp2f(v[j] - m) : 0.f;
    v[j] = e;
    sum += e;
  }
#pragma unroll
  for (int o = 32; o > 0; o >>= 1) sum += __shfl_xor(sum, o, 64);
  if (lane == 0) red[wid] = sum;
  __syncthreads();
  sum = red[0] + red[1] + red[2] + red[3];
  float inv = 1.0f / sum;
  us8 outv;
#pragma unroll
  for (int j = 0; j < 8; ++j) outv[j] = f2bf(v[j] * inv);
  *(us8*)(row + s0) = outv;
}

extern "C" void kernel_launch(void* const* d_in, const int* in_sizes, int n_in,
                              void* d_out, int out_size, void* d_ws, size_t ws_size,
                              hipStream_t stream) {
  const float* x = (const float*)d_in[0];      // [4,2048,1024]
  const float* W = (const float*)d_in[1];      // [3072,1024]
  const float* bias = (const float*)d_in[2];   // [3072]
  float* out = (float*)d_out;                  // [4,2048,1024]

  char* ws = (char*)d_ws;
  // layout (bytes): xbf 16,777,216 (aliased by vT after gemm1) | wbf 6,291,456 |
  //                 kqv 50,331,648 | S 33,554,432  => 106,954,752 total
  if (ws_size < 106954752u) return;
  unsigned short* xbf = (unsigned short*)(ws);
  unsigned short* vT = xbf;  // alias: xbf dead after gemm<0>; stream order protects
  unsigned short* wbf = (unsigned short*)(ws + 16777216);
  unsigned short* kqv = (unsigned short*)(ws + 23068672);
  unsigned short* S = (unsigned short*)(ws + 73400320);

  const float kSoftmaxScale = 1.4426950408889634f / 32.0f;  // log2(e)/sqrt(1024)

  cvt_bf16<<<8192, 256, 0, stream>>>(x, xbf, 8388608 / 4);
  cvt_bf16<<<3072, 256, 0, stream>>>(W, wbf, 3145728 / 4);

  // kqv = x @ W^T + b   (M=8192, N=3072, K=1024)
  gemm_bt<0><<<dim3(24, 64, 1), 256, 0, stream>>>(
      xbf, 1024, 0LL, wbf, 1024, 0LL, kqv, 3072, 0LL, bias, 1.0f, 1024);

  // vT[b][c][t] from v = kqv[:, 2048:3072]
  transpose_v<<<dim3(32, 16, 4), 256, 0, stream>>>(kqv, vT);

  // S = (k @ q^T) * log2e/32, bf16; k = kqv[:, :1024], q = kqv[:, 1024:2048]
  gemm_bt<1><<<dim3(16, 16, 4), 256, 0, stream>>>(
      kqv, 3072, 2048LL * 3072, kqv + 1024, 3072, 2048LL * 3072,
      S, 2048, 2048LL * 2048, nullptr, kSoftmaxScale, 1024);

  // causal softmax rows, in place (P bf16)
  softmax_causal<<<dim3(2048, 4), 256, 0, stream>>>(S);

  // out = P @ vT^T  (M=2048, N=1024, K=2048 truncated at diagonal), fp32
  gemm_bt<2><<<dim3(8, 16, 4), 256, 0, stream>>>(
      S, 2048, 2048LL * 2048, vT, 2048, 1024LL * 2048,
      out, 1024, 2048LL * 1024, nullptr, 1.0f, 2048);
}

// Round 2
// 195.401 us; speedup vs baseline: 1.1258x; 1.1258x over previous
//
#include <hip/hip_runtime.h>

typedef __bf16 bf16x8 __attribute__((ext_vector_type(8)));
typedef float f32x4 __attribute__((ext_vector_type(4)));
typedef float fl4 __attribute__((ext_vector_type(4)));
typedef unsigned short us4 __attribute__((ext_vector_type(4)));
typedef unsigned short us8 __attribute__((ext_vector_type(8)));

__device__ __forceinline__ unsigned short f2bf(float f) {
  unsigned u = __builtin_bit_cast(unsigned, f);
  u += 0x7fffu + ((u >> 16) & 1u);
  return (unsigned short)(u >> 16);
}
__device__ __forceinline__ float bf2f(unsigned short h) {
  unsigned u = ((unsigned)h) << 16;
  return __builtin_bit_cast(float, u);
}

__device__ __forceinline__ void async16(const void* g, void* l) {
  __builtin_amdgcn_global_load_lds(
      (const __attribute__((address_space(1))) unsigned int*)g,
      (__attribute__((address_space(3))) unsigned int*)l, 16, 0, 0);
}

#define BARM() asm volatile("s_barrier" ::: "memory")
#define VMCNT4() asm volatile("s_waitcnt vmcnt(4)" ::: "memory")
#define VMCNT0() asm volatile("s_waitcnt vmcnt(0)" ::: "memory")

// ---------------- fp32 -> bf16 convert ----------------
__global__ __launch_bounds__(256) void cvt_bf16(const float* __restrict__ s,
                                                unsigned short* __restrict__ d, int n4) {
  int i = blockIdx.x * 256 + threadIdx.x;
  if (i >= n4) return;
  fl4 f = ((const fl4*)s)[i];
  us4 o;
  o[0] = f2bf(f[0]); o[1] = f2bf(f[1]); o[2] = f2bf(f[2]); o[3] = f2bf(f[3]);
  ((us4*)d)[i] = o;
}

// ---------------- transpose v: vT[b][c][t] = kqv[b*2048+t][2048+c] ----------------
__global__ __launch_bounds__(256) void transpose_v(const unsigned short* __restrict__ kqv,
                                                   unsigned short* __restrict__ vT) {
  int b = blockIdx.z;
  int t0 = blockIdx.x * 64;
  int c0 = blockIdx.y * 64;
  __shared__ unsigned short tile[64][68];
  int tid = threadIdx.x;
#pragma unroll
  for (int i = 0; i < 4; ++i) {
    int idx = i * 256 + tid;
    int r = idx >> 4;
    int c4 = (idx & 15) * 4;
    const unsigned short* src = kqv + ((size_t)(b * 2048 + t0 + r)) * 3072 + 2048 + c0 + c4;
    us4 v = *(const us4*)src;
    *(us4*)&tile[r][c4] = v;
  }
  __syncthreads();
#pragma unroll
  for (int i = 0; i < 4; ++i) {
    int idx = i * 256 + tid;
    int rc = idx >> 4;
    int t4 = (idx & 15) * 4;
    us4 v;
    v[0] = tile[t4 + 0][rc]; v[1] = tile[t4 + 1][rc];
    v[2] = tile[t4 + 2][rc]; v[3] = tile[t4 + 3][rc];
    unsigned short* dst = vT + ((size_t)(b * 1024 + c0 + rc)) * 2048 + t0 + t4;
    *(us4*)dst = v;
  }
}

// ---------------- 256x256 8-phase bf16 MFMA GEMM (B^T format both operands) ----
// 8 waves (2M x 4N), BK=64, LDS 128KB: 2 bufs x (A 32KB | B 32KB), halves of 16KB.
// Schedule per iteration (2 K-tiles), computing t from buf0 then t+1 from buf1:
//   ph1: rd B-frags+A01(buf0); issue A-h0(t+1)->buf1
//   ph2: rd A23(buf0);         issue A-h1(t+1)->buf1
//   ph3: rd A45(buf0);         issue B-h0(t+2)->buf0   (buf0.B dead after ph1)
//   ph4: rd A67(buf0);         issue B-h1(t+2)->buf0 ; vmcnt(4) gate (buf1 ready)
//   ph5-8: symmetric (A(t+2)->buf0, B(t+3)->buf1; gate for buf0)
// Raw s_barrier (no vmcnt drain); "memory" clobber pins loads into their phase.
// EPI 0: bf16 out + bias. EPI 1: bf16 out * scale, skip blocks above diagonal.
// EPI 2: f32 out, K truncated at diagonal (nk = (rowBase+256)/64, always even).

template <int EPI>
__global__ __launch_bounds__(512, 2) void gemm8p(
    const unsigned short* __restrict__ A, int lda, long long sA,
    const unsigned short* __restrict__ B, int ldb, long long sB,
    void* __restrict__ Cv, int ldc, long long sC,
    const float* __restrict__ bias, float scale, int K, int NBX) {
  int bx, by;
  const int bz = blockIdx.z;
  if (EPI == 0) {
    int flat = blockIdx.x;
    int q = (int)gridDim.x >> 3;            // grid %8 == 0
    int swz = (flat & 7) * q + (flat >> 3); // XCD-contiguous remap
    bx = swz % NBX; by = swz / NBX;
  } else {
    bx = blockIdx.x; by = blockIdx.y;
    if (EPI == 1 && bx > by) return;
  }
  A += (size_t)bz * sA;
  B += (size_t)bz * sB;
  const int rowBase = by * 256;
  const int colBase = bx * 256;
  const int nk = (EPI == 2) ? (rowBase + 256) / 64 : K / 64;

  __shared__ __align__(16) unsigned char lds[131072];
  const int tid = threadIdx.x;
  const int lane = tid & 63;
  const int wid = tid >> 6;
  const int wr = wid >> 2;   // 0..1
  const int wc = wid & 3;    // 0..3
  const int l15 = lane & 15, l4 = lane >> 4, l7 = lane & 7;

  f32x4 acc[8][4] = {};
  bf16x8 bfr[4][2];

  // stage one half-tile (128 rows x 64 K) via global_load_lds, linear LDS dest,
  // pre-swizzled global source: LDS block b of row r holds global block b^(r&7).
  auto STAGE = [&](int bufc, int isB, int half, const unsigned short* G, int ld,
                   int rbase, int koff) {
#pragma unroll
    for (int i = 0; i < 2; ++i) {
      int off = (i * 512 + tid) * 16;
      int r = off >> 7;
      int sb = ((off >> 4) & 7) ^ (r & 7);
      async16(G + (size_t)(rbase + half * 128 + r) * ld + koff + sb * 8,
              lds + bufc * 65536 + isB * 32768 + half * 16384 + off);
    }
  };
  auto RDA = [&](int bufc, int m, int kk) -> bf16x8 {
    int row = m * 16 + l15;                    // within this wave's 128-row half
    int blk = (kk * 4 + l4) ^ l7;
    return *(const bf16x8*)(lds + bufc * 65536 + wr * 16384 + row * 128 + blk * 16);
  };
  auto RDB = [&](int bufc, int n, int kk) -> bf16x8 {
    int row = (wc & 1) * 64 + n * 16 + l15;    // within B half (wc>>1)
    int blk = (kk * 4 + l4) ^ l7;
    return *(const bf16x8*)(lds + bufc * 65536 + 32768 + (wc >> 1) * 16384 +
                            row * 128 + blk * 16);
  };

#define PHASE(BUFC, Q, STAGE_STMT, GATE_STMT)                                  \
  do {                                                                         \
    bf16x8 af[2][2];                                                           \
    if ((Q) == 0) {                                                            \
      _Pragma("unroll") for (int n = 0; n < 4; ++n)                            \
      _Pragma("unroll") for (int kk = 0; kk < 2; ++kk)                         \
          bfr[n][kk] = RDB((BUFC), n, kk);                                     \
    }                                                                          \
    _Pragma("unroll") for (int mi = 0; mi < 2; ++mi)                           \
    _Pragma("unroll") for (int kk = 0; kk < 2; ++kk)                           \
        af[mi][kk] = RDA((BUFC), (Q) * 2 + mi, kk);                            \
    STAGE_STMT;                                                                \
    BARM();                                                                    \
    __builtin_amdgcn_s_setprio(1);                                             \
    _Pragma("unroll") for (int kk = 0; kk < 2; ++kk)                           \
    _Pragma("unroll") for (int mi = 0; mi < 2; ++mi)                           \
    _Pragma("unroll") for (int n = 0; n < 4; ++n)                              \
        acc[(Q) * 2 + mi][n] = __builtin_amdgcn_mfma_f32_16x16x32_bf16(        \
            af[mi][kk], bfr[n][kk], acc[(Q) * 2 + mi][n], 0, 0, 0);            \
    __builtin_amdgcn_s_setprio(0);                                             \
    GATE_STMT;                                                                 \
    BARM();                                                                    \
  } while (0)

  // prologue: tile0 (A,B)->buf0, tile1 B->buf1; allow tile1's B in flight
  STAGE(0, 0, 0, A, lda, rowBase, 0);
  STAGE(0, 0, 1, A, lda, rowBase, 0);
  STAGE(0, 1, 0, B, ldb, colBase, 0);
  STAGE(0, 1, 1, B, ldb, colBase, 0);
  {
    int k1 = ((1 < nk - 1) ? 1 : (nk - 1)) * 64;
    STAGE(1, 1, 0, B, ldb, colBase, k1);
    STAGE(1, 1, 1, B, ldb, colBase, k1);
  }
  VMCNT4();
  BARM();

  const int nt2 = nk >> 1;
  for (int it = 0; it < nt2; ++it) {
    int t = it * 2;
    int tA1 = t + 1 < nk - 1 ? t + 1 : nk - 1;
    int t2 = t + 2 < nk - 1 ? t + 2 : nk - 1;
    int t3 = t + 3 < nk - 1 ? t + 3 : nk - 1;
    int kA1 = tA1 * 64, k2 = t2 * 64, k3 = t3 * 64;
    PHASE(0, 0, STAGE(1, 0, 0, A, lda, rowBase, kA1), (void)0);
    PHASE(0, 1, STAGE(1, 0, 1, A, lda, rowBase, kA1), (void)0);
    PHASE(0, 2, STAGE(0, 1, 0, B, ldb, colBase, k2), (void)0);
    PHASE(0, 3, STAGE(0, 1, 1, B, ldb, colBase, k2), VMCNT4());
    PHASE(1, 0, STAGE(0, 0, 0, A, lda, rowBase, k2), (void)0);
    PHASE(1, 1, STAGE(0, 0, 1, A, lda, rowBase, k2), (void)0);
    PHASE(1, 2, STAGE(1, 1, 0, B, ldb, colBase, k3), (void)0);
    PHASE(1, 3, STAGE(1, 1, 1, B, ldb, colBase, k3), VMCNT0());
  }
#undef PHASE

  const int cr = l4 * 4;
  if constexpr (EPI == 0) {
    unsigned short* C = (unsigned short*)Cv;
#pragma unroll
    for (int n = 0; n < 4; ++n) {
      int col = colBase + wc * 64 + n * 16 + l15;
      float bv = bias[col];
#pragma unroll
      for (int m = 0; m < 8; ++m) {
        int row = rowBase + wr * 128 + m * 16 + cr;
#pragma unroll
        for (int i = 0; i < 4; ++i)
          C[(size_t)(row + i) * ldc + col] = f2bf(acc[m][n][i] + bv);
      }
    }
  } else if constexpr (EPI == 1) {
    unsigned short* C = (unsigned short*)Cv + (size_t)bz * sC;
#pragma unroll
    for (int n = 0; n < 4; ++n) {
      int col = colBase + wc * 64 + n * 16 + l15;
#pragma unroll
      for (int m = 0; m < 8; ++m) {
        int row = rowBase + wr * 128 + m * 16 + cr;
#pragma unroll
        for (int i = 0; i < 4; ++i)
          C[(size_t)(row + i) * ldc + col] = f2bf(acc[m][n][i] * scale);
      }
    }
  } else {
    float* C = (float*)Cv + (size_t)bz * sC;
#pragma unroll
    for (int n = 0; n < 4; ++n) {
      int col = colBase + wc * 64 + n * 16 + l15;
#pragma unroll
      for (int m = 0; m < 8; ++m) {
        int row = rowBase + wr * 128 + m * 16 + cr;
#pragma unroll
        for (int i = 0; i < 4; ++i)
          C[(size_t)(row + i) * ldc + col] = acc[m][n][i];
      }
    }
  }
}

// ---------------- causal softmax over S rows (in place, bf16) ----------------
__global__ __launch_bounds__(256) void softmax_causal(unsigned short* __restrict__ S) {
  const int T = 2048;
  int t = blockIdx.x, b = blockIdx.y;
  unsigned short* row = S + ((size_t)b * T + t) * T;
  const int nv = t + 1;
  int tid = threadIdx.x;
  int lane = tid & 63, wid = tid >> 6;
  int s0 = tid * 8;
  us8 raw = *(const us8*)(row + s0);
  float v[8];
  float m = -3.0e38f;
#pragma unroll
  for (int j = 0; j < 8; ++j) {
    v[j] = bf2f(raw[j]);
    if (s0 + j < nv) m = fmaxf(m, v[j]);
  }
#pragma unroll
  for (int o = 32; o > 0; o >>= 1) m = fmaxf(m, __shfl_xor(m, o, 64));
  __shared__ float red[4];
  if (lane == 0) red[wid] = m;
  __syncthreads();
  m = fmaxf(fmaxf(red[0], red[1]), fmaxf(red[2], red[3]));
  __syncthreads();
  float sum = 0.f;
#pragma unroll
  for (int j = 0; j < 8; ++j) {
    float e = (s0 + j < nv) ? exp2f(v[j] - m) : 0.f;
    v[j] = e;
    sum += e;
  }
#pragma unroll
  for (int o = 32; o > 0; o >>= 1) sum += __shfl_xor(sum, o, 64);
  if (lane == 0) red[wid] = sum;
  __syncthreads();
  sum = red[0] + red[1] + red[2] + red[3];
  float inv = 1.0f / sum;
  us8 outv;
#pragma unroll
  for (int j = 0; j < 8; ++j) outv[j] = f2bf(v[j] * inv);
  *(us8*)(row + s0) = outv;
}

extern "C" void kernel_launch(void* const* d_in, const int* in_sizes, int n_in,
                              void* d_out, int out_size, void* d_ws, size_t ws_size,
                              hipStream_t stream) {
  const float* x = (const float*)d_in[0];      // [4,2048,1024]
  const float* W = (const float*)d_in[1];      // [3072,1024]
  const float* bias = (const float*)d_in[2];   // [3072]
  float* out = (float*)d_out;                  // [4,2048,1024]

  char* ws = (char*)d_ws;
  // layout: xbf 16MB (aliased by vT after gemm0) | wbf 6MB | kqv 48MB | S 32MB
  if (ws_size < 106954752u) return;
  unsigned short* xbf = (unsigned short*)(ws);
  unsigned short* vT = xbf;  // alias: xbf dead after gemm8p<0>
  unsigned short* wbf = (unsigned short*)(ws + 16777216);
  unsigned short* kqv = (unsigned short*)(ws + 23068672);
  unsigned short* S = (unsigned short*)(ws + 73400320);

  const float kSoftmaxScale = 1.4426950408889634f / 32.0f;  // log2(e)/sqrt(1024)

  cvt_bf16<<<8192, 256, 0, stream>>>(x, xbf, 2097152);
  cvt_bf16<<<3072, 256, 0, stream>>>(W, wbf, 786432);

  // kqv = x @ W^T + b   (M=8192, N=3072, K=1024) ; grid 32x12 = 384, XCD swizzle
  gemm8p<0><<<dim3(384, 1, 1), 512, 0, stream>>>(
      xbf, 1024, 0LL, wbf, 1024, 0LL, kqv, 3072, 0LL, bias, 1.0f, 1024, 12);

  transpose_v<<<dim3(32, 16, 4), 256, 0, stream>>>(kqv, vT);

  // S = (k @ q^T) * log2e/32 (bf16), causal blocks skipped
  gemm8p<1><<<dim3(8, 8, 4), 512, 0, stream>>>(
      kqv, 3072, 2048LL * 3072, kqv + 1024, 3072, 2048LL * 3072,
      S, 2048, 2048LL * 2048, nullptr, kSoftmaxScale, 1024, 0);

  softmax_causal<<<dim3(2048, 4), 256, 0, stream>>>(S);

  // out = P @ vT^T (fp32), K truncated at diagonal
  gemm8p<2><<<dim3(4, 8, 4), 512, 0, stream>>>(
      S, 2048, 2048LL * 2048, vT, 2048, 1024LL * 2048,
      out, 1024, 2048LL * 1024, nullptr, 1.0f, 2048, 0);
}

// Round 3
// 192.410 us; speedup vs baseline: 1.1433x; 1.0155x over previous
//
#include <hip/hip_runtime.h>

typedef __bf16 bf16x8 __attribute__((ext_vector_type(8)));
typedef float f32x4 __attribute__((ext_vector_type(4)));
typedef float fl4 __attribute__((ext_vector_type(4)));
typedef unsigned short us4 __attribute__((ext_vector_type(4)));
typedef unsigned short us8 __attribute__((ext_vector_type(8)));

__device__ __forceinline__ unsigned short f2bf(float f) {
  unsigned u = __builtin_bit_cast(unsigned, f);
  u += 0x7fffu + ((u >> 16) & 1u);
  return (unsigned short)(u >> 16);
}
__device__ __forceinline__ float bf2f(unsigned short h) {
  unsigned u = ((unsigned)h) << 16;
  return __builtin_bit_cast(float, u);
}

__device__ __forceinline__ void async16(const void* g, void* l) {
  __builtin_amdgcn_global_load_lds(
      (const __attribute__((address_space(1))) unsigned int*)g,
      (__attribute__((address_space(3))) unsigned int*)l, 16, 0, 0);
}

#define BARM() asm volatile("s_barrier" ::: "memory")
#define VMCNT4() asm volatile("s_waitcnt vmcnt(4)" ::: "memory")

// ---------------- fp32 -> bf16 convert ----------------
__global__ __launch_bounds__(256) void cvt_bf16(const float* __restrict__ s,
                                                unsigned short* __restrict__ d, int n4) {
  int i = blockIdx.x * 256 + threadIdx.x;
  if (i >= n4) return;
  fl4 f = ((const fl4*)s)[i];
  us4 o;
  o[0] = f2bf(f[0]); o[1] = f2bf(f[1]); o[2] = f2bf(f[2]); o[3] = f2bf(f[3]);
  ((us4*)d)[i] = o;
}

// ---------------- transpose v: vT[b][c][t] = kqv[b*2048+t][2048+c] ----------------
__global__ __launch_bounds__(256) void transpose_v(const unsigned short* __restrict__ kqv,
                                                   unsigned short* __restrict__ vT) {
  int b = blockIdx.z;
  int t0 = blockIdx.x * 64;
  int c0 = blockIdx.y * 64;
  __shared__ unsigned short tile[64][68];
  int tid = threadIdx.x;
#pragma unroll
  for (int i = 0; i < 4; ++i) {
    int idx = i * 256 + tid;
    int r = idx >> 4;
    int c4 = (idx & 15) * 4;
    const unsigned short* src = kqv + ((size_t)(b * 2048 + t0 + r)) * 3072 + 2048 + c0 + c4;
    us4 v = *(const us4*)src;
    *(us4*)&tile[r][c4] = v;
  }
  __syncthreads();
#pragma unroll
  for (int i = 0; i < 4; ++i) {
    int idx = i * 256 + tid;
    int rc = idx >> 4;
    int t4 = (idx & 15) * 4;
    us4 v;
    v[0] = tile[t4 + 0][rc]; v[1] = tile[t4 + 1][rc];
    v[2] = tile[t4 + 2][rc]; v[3] = tile[t4 + 3][rc];
    unsigned short* dst = vT + ((size_t)(b * 1024 + c0 + rc)) * 2048 + t0 + t4;
    *(us4*)dst = v;
  }
}

// ---------------- 256x256 8-phase bf16 MFMA GEMM (B^T format both operands) ----
// 8 waves (2M x 4N), BK=64, LDS 128KB: 2 bufs x (A 32KB | B 32KB), halves of 16KB.
// Steady-state queue (2 vmem ops per STAGE, FIFO per wave):
//   ph4 gate: [B(t+1)h0,h1, A(t+1)h0,h1, B(t+2)h0,h1] -> vmcnt(4) => buf1 ready
//   ph8 gate: [B(t+2)h0,h1, A(t+2)h0,h1, B(t+3)h0,h1] -> vmcnt(4) => buf0 ready
// NEVER vmcnt(0) in the main loop (m218: drain-0 ~= 1-phase).
// Raw s_barrier (no vmcnt drain); "memory" clobber pins loads into their phase.
// EPI 0: bf16 out + bias. EPI 1: bf16 out * scale, skip blocks above diagonal.
// EPI 2: f32 out, K truncated at diagonal (nk = (rowBase+256)/64, always even).

template <int EPI>
__global__ __launch_bounds__(512, 2) void gemm8p(
    const unsigned short* __restrict__ A, int lda, long long sA,
    const unsigned short* __restrict__ B, int ldb, long long sB,
    void* __restrict__ Cv, int ldc, long long sC,
    const float* __restrict__ bias, float scale, int K, int NBX) {
  int bx, by;
  const int bz = blockIdx.z;
  if (EPI == 0) {
    int flat = blockIdx.x;
    int q = (int)gridDim.x >> 3;            // grid %8 == 0
    int swz = (flat & 7) * q + (flat >> 3); // XCD-contiguous remap
    bx = swz % NBX; by = swz / NBX;
  } else {
    bx = blockIdx.x; by = blockIdx.y;
    if (EPI == 1 && bx > by) return;
  }
  A += (size_t)bz * sA;
  B += (size_t)bz * sB;
  const int rowBase = by * 256;
  const int colBase = bx * 256;
  const int nk = (EPI == 2) ? (rowBase + 256) / 64 : K / 64;

  __shared__ __align__(16) unsigned char lds[131072];
  const int tid = threadIdx.x;
  const int lane = tid & 63;
  const int wid = tid >> 6;
  const int wr = wid >> 2;   // 0..1
  const int wc = wid & 3;    // 0..3
  const int l15 = lane & 15, l4 = lane >> 4, l7 = lane & 7;

  f32x4 acc[8][4] = {};
  bf16x8 bfr[4][2];

  // stage one half-tile (128 rows x 64 K) via global_load_lds, linear LDS dest,
  // pre-swizzled global source: LDS block b of row r holds global block b^(r&7).
  auto STAGE = [&](int bufc, int isB, int half, const unsigned short* G, int ld,
                   int rbase, int koff) {
#pragma unroll
    for (int i = 0; i < 2; ++i) {
      int off = (i * 512 + tid) * 16;
      int r = off >> 7;
      int sb = ((off >> 4) & 7) ^ (r & 7);
      async16(G + (size_t)(rbase + half * 128 + r) * ld + koff + sb * 8,
              lds + bufc * 65536 + isB * 32768 + half * 16384 + off);
    }
  };
  auto RDA = [&](int bufc, int m, int kk) -> bf16x8 {
    int row = m * 16 + l15;                    // within this wave's 128-row half
    int blk = (kk * 4 + l4) ^ l7;
    return *(const bf16x8*)(lds + bufc * 65536 + wr * 16384 + row * 128 + blk * 16);
  };
  auto RDB = [&](int bufc, int n, int kk) -> bf16x8 {
    int row = (wc & 1) * 64 + n * 16 + l15;    // within B half (wc>>1)
    int blk = (kk * 4 + l4) ^ l7;
    return *(const bf16x8*)(lds + bufc * 65536 + 32768 + (wc >> 1) * 16384 +
                            row * 128 + blk * 16);
  };

#define PHASE(BUFC, Q, STAGE_STMT, GATE_STMT)                                  \
  do {                                                                         \
    bf16x8 af[2][2];                                                           \
    if ((Q) == 0) {                                                            \
      _Pragma("unroll") for (int n = 0; n < 4; ++n)                            \
      _Pragma("unroll") for (int kk = 0; kk < 2; ++kk)                         \
          bfr[n][kk] = RDB((BUFC), n, kk);                                     \
    }                                                                          \
    _Pragma("unroll") for (int mi = 0; mi < 2; ++mi)                           \
    _Pragma("unroll") for (int kk = 0; kk < 2; ++kk)                           \
        af[mi][kk] = RDA((BUFC), (Q) * 2 + mi, kk);                            \
    STAGE_STMT;                                                                \
    BARM();                                                                    \
    __builtin_amdgcn_s_setprio(1);                                             \
    _Pragma("unroll") for (int kk = 0; kk < 2; ++kk)                           \
    _Pragma("unroll") for (int mi = 0; mi < 2; ++mi)                           \
    _Pragma("unroll") for (int n = 0; n < 4; ++n)                              \
        acc[(Q) * 2 + mi][n] = __builtin_amdgcn_mfma_f32_16x16x32_bf16(        \
            af[mi][kk], bfr[n][kk], acc[(Q) * 2 + mi][n], 0, 0, 0);            \
    __builtin_amdgcn_s_setprio(0);                                             \
    GATE_STMT;                                                                 \
    BARM();                                                                    \
  } while (0)

  // prologue: tile0 (A,B)->buf0, tile1 B->buf1; gate leaves tile1's B in flight
  STAGE(0, 0, 0, A, lda, rowBase, 0);
  STAGE(0, 0, 1, A, lda, rowBase, 0);
  STAGE(0, 1, 0, B, ldb, colBase, 0);
  STAGE(0, 1, 1, B, ldb, colBase, 0);
  {
    int k1 = ((1 < nk - 1) ? 1 : (nk - 1)) * 64;
    STAGE(1, 1, 0, B, ldb, colBase, k1);
    STAGE(1, 1, 1, B, ldb, colBase, k1);
  }
  VMCNT4();
  BARM();

  const int nt2 = nk >> 1;
  for (int it = 0; it < nt2; ++it) {
    int t = it * 2;
    int tA1 = t + 1 < nk - 1 ? t + 1 : nk - 1;
    int t2 = t + 2 < nk - 1 ? t + 2 : nk - 1;
    int t3 = t + 3 < nk - 1 ? t + 3 : nk - 1;
    int kA1 = tA1 * 64, k2 = t2 * 64, k3 = t3 * 64;
    PHASE(0, 0, STAGE(1, 0, 0, A, lda, rowBase, kA1), (void)0);
    PHASE(0, 1, STAGE(1, 0, 1, A, lda, rowBase, kA1), (void)0);
    PHASE(0, 2, STAGE(0, 1, 0, B, ldb, colBase, k2), (void)0);
    PHASE(0, 3, STAGE(0, 1, 1, B, ldb, colBase, k2), VMCNT4());
    PHASE(1, 0, STAGE(0, 0, 0, A, lda, rowBase, k2), (void)0);
    PHASE(1, 1, STAGE(0, 0, 1, A, lda, rowBase, k2), (void)0);
    PHASE(1, 2, STAGE(1, 1, 0, B, ldb, colBase, k3), (void)0);
    PHASE(1, 3, STAGE(1, 1, 1, B, ldb, colBase, k3), VMCNT4());
  }
#undef PHASE

  const int cr = l4 * 4;
  if constexpr (EPI == 0) {
    unsigned short* C = (unsigned short*)Cv;
#pragma unroll
    for (int n = 0; n < 4; ++n) {
      int col = colBase + wc * 64 + n * 16 + l15;
      float bv = bias[col];
#pragma unroll
      for (int m = 0; m < 8; ++m) {
        int row = rowBase + wr * 128 + m * 16 + cr;
#pragma unroll
        for (int i = 0; i < 4; ++i)
          C[(size_t)(row + i) * ldc + col] = f2bf(acc[m][n][i] + bv);
      }
    }
  } else if constexpr (EPI == 1) {
    unsigned short* C = (unsigned short*)Cv + (size_t)bz * sC;
#pragma unroll
    for (int n = 0; n < 4; ++n) {
      int col = colBase + wc * 64 + n * 16 + l15;
#pragma unroll
      for (int m = 0; m < 8; ++m) {
        int row = rowBase + wr * 128 + m * 16 + cr;
#pragma unroll
        for (int i = 0; i < 4; ++i)
          C[(size_t)(row + i) * ldc + col] = f2bf(acc[m][n][i] * scale);
      }
    }
  } else {
    float* C = (float*)Cv + (size_t)bz * sC;
#pragma unroll
    for (int n = 0; n < 4; ++n) {
      int col = colBase + wc * 64 + n * 16 + l15;
#pragma unroll
      for (int m = 0; m < 8; ++m) {
        int row = rowBase + wr * 128 + m * 16 + cr;
#pragma unroll
        for (int i = 0; i < 4; ++i)
          C[(size_t)(row + i) * ldc + col] = acc[m][n][i];
      }
    }
  }
}

// ---------------- causal softmax over S rows (in place, bf16) ----------------
__global__ __launch_bounds__(256) void softmax_causal(unsigned short* __restrict__ S) {
  const int T = 2048;
  int t = blockIdx.x, b = blockIdx.y;
  unsigned short* row = S + ((size_t)b * T + t) * T;
  const int nv = t + 1;
  int tid = threadIdx.x;
  int lane = tid & 63, wid = tid >> 6;
  int s0 = tid * 8;
  us8 raw = *(const us8*)(row + s0);
  float v[8];
  float m = -3.0e38f;
#pragma unroll
  for (int j = 0; j < 8; ++j) {
    v[j] = bf2f(raw[j]);
    if (s0 + j < nv) m = fmaxf(m, v[j]);
  }
#pragma unroll
  for (int o = 32; o > 0; o >>= 1) m = fmaxf(m, __shfl_xor(m, o, 64));
  __shared__ float red[4];
  if (lane == 0) red[wid] = m;
  __syncthreads();
  m = fmaxf(fmaxf(red[0], red[1]), fmaxf(red[2], red[3]));
  __syncthreads();
  float sum = 0.f;
#pragma unroll
  for (int j = 0; j < 8; ++j) {
    float e = (s0 + j < nv) ? exp2f(v[j] - m) : 0.f;
    v[j] = e;
    sum += e;
  }
#pragma unroll
  for (int o = 32; o > 0; o >>= 1) sum += __shfl_xor(sum, o, 64);
  if (lane == 0) red[wid] = sum;
  __syncthreads();
  sum = red[0] + red[1] + red[2] + red[3];
  float inv = 1.0f / sum;
  us8 outv;
#pragma unroll
  for (int j = 0; j < 8; ++j) outv[j] = f2bf(v[j] * inv);
  *(us8*)(row + s0) = outv;
}

extern "C" void kernel_launch(void* const* d_in, const int* in_sizes, int n_in,
                              void* d_out, int out_size, void* d_ws, size_t ws_size,
                              hipStream_t stream) {
  const float* x = (const float*)d_in[0];      // [4,2048,1024]
  const float* W = (const float*)d_in[1];      // [3072,1024]
  const float* bias = (const float*)d_in[2];   // [3072]
  float* out = (float*)d_out;                  // [4,2048,1024]

  char* ws = (char*)d_ws;
  // layout: xbf 16MB (aliased by vT after gemm0) | wbf 6MB | kqv 48MB | S 32MB
  if (ws_size < 106954752u) return;
  unsigned short* xbf = (unsigned short*)(ws);
  unsigned short* vT = xbf;  // alias: xbf dead after gemm8p<0>
  unsigned short* wbf = (unsigned short*)(ws + 16777216);
  unsigned short* kqv = (unsigned short*)(ws + 23068672);
  unsigned short* S = (unsigned short*)(ws + 73400320);

  const float kSoftmaxScale = 1.4426950408889634f / 32.0f;  // log2(e)/sqrt(1024)

  cvt_bf16<<<8192, 256, 0, stream>>>(x, xbf, 2097152);
  cvt_bf16<<<3072, 256, 0, stream>>>(W, wbf, 786432);

  // kqv = x @ W^T + b   (M=8192, N=3072, K=1024) ; grid 32x12 = 384, XCD swizzle
  gemm8p<0><<<dim3(384, 1, 1), 512, 0, stream>>>(
      xbf, 1024, 0LL, wbf, 1024, 0LL, kqv, 3072, 0LL, bias, 1.0f, 1024, 12);

  transpose_v<<<dim3(32, 16, 4), 256, 0, stream>>>(kqv, vT);

  // S = (k @ q^T) * log2e/32 (bf16), causal blocks skipped
  gemm8p<1><<<dim3(8, 8, 4), 512, 0, stream>>>(
      kqv, 3072, 2048LL * 3072, kqv + 1024, 3072, 2048LL * 3072,
      S, 2048, 2048LL * 2048, nullptr, kSoftmaxScale, 1024, 0);

  softmax_causal<<<dim3(2048, 4), 256, 0, stream>>>(S);

  // out = P @ vT^T (fp32), K truncated at diagonal
  gemm8p<2><<<dim3(4, 8, 4), 512, 0, stream>>>(
      S, 2048, 2048LL * 2048, vT, 2048, 1024LL * 2048,
      out, 1024, 2048LL * 1024, nullptr, 1.0f, 2048, 0);
}

// Round 4
// 189.674 us; speedup vs baseline: 1.1598x; 1.0144x over previous
//
#include <hip/hip_runtime.h>

typedef __bf16 bf16x8 __attribute__((ext_vector_type(8)));
typedef float f32x4 __attribute__((ext_vector_type(4)));
typedef float fl4 __attribute__((ext_vector_type(4)));
typedef unsigned short us4 __attribute__((ext_vector_type(4)));
typedef unsigned short us8 __attribute__((ext_vector_type(8)));

__device__ __forceinline__ unsigned short f2bf(float f) {
  unsigned u = __builtin_bit_cast(unsigned, f);
  u += 0x7fffu + ((u >> 16) & 1u);
  return (unsigned short)(u >> 16);
}
__device__ __forceinline__ float bf2f(unsigned short h) {
  unsigned u = ((unsigned)h) << 16;
  return __builtin_bit_cast(float, u);
}

__device__ __forceinline__ void async16(const void* g, void* l) {
  __builtin_amdgcn_global_load_lds(
      (const __attribute__((address_space(1))) unsigned int*)g,
      (__attribute__((address_space(3))) unsigned int*)l, 16, 0, 0);
}

#define BARM() asm volatile("s_barrier" ::: "memory")
#define VMCNT4() asm volatile("s_waitcnt vmcnt(4)" ::: "memory")
#define LGKM0() asm volatile("s_waitcnt lgkmcnt(0)" ::: "memory")

// ---------------- fp32 -> bf16 convert ----------------
__global__ __launch_bounds__(256) void cvt_bf16(const float* __restrict__ s,
                                                unsigned short* __restrict__ d, int n4) {
  int i = blockIdx.x * 256 + threadIdx.x;
  if (i >= n4) return;
  fl4 f = ((const fl4*)s)[i];
  us4 o;
  o[0] = f2bf(f[0]); o[1] = f2bf(f[1]); o[2] = f2bf(f[2]); o[3] = f2bf(f[3]);
  ((us4*)d)[i] = o;
}

// ---------------- transpose v: vT[b][c][t] = kqv[b*2048+t][2048+c] ----------------
__global__ __launch_bounds__(256) void transpose_v(const unsigned short* __restrict__ kqv,
                                                   unsigned short* __restrict__ vT) {
  int b = blockIdx.z;
  int t0 = blockIdx.x * 64;
  int c0 = blockIdx.y * 64;
  __shared__ unsigned short tile[64][68];
  int tid = threadIdx.x;
#pragma unroll
  for (int i = 0; i < 4; ++i) {
    int idx = i * 256 + tid;
    int r = idx >> 4;
    int c4 = (idx & 15) * 4;
    const unsigned short* src = kqv + ((size_t)(b * 2048 + t0 + r)) * 3072 + 2048 + c0 + c4;
    us4 v = *(const us4*)src;
    *(us4*)&tile[r][c4] = v;
  }
  __syncthreads();
#pragma unroll
  for (int i = 0; i < 4; ++i) {
    int idx = i * 256 + tid;
    int rc = idx >> 4;
    int t4 = (idx & 15) * 4;
    us4 v;
    v[0] = tile[t4 + 0][rc]; v[1] = tile[t4 + 1][rc];
    v[2] = tile[t4 + 2][rc]; v[3] = tile[t4 + 3][rc];
    unsigned short* dst = vT + ((size_t)(b * 1024 + c0 + rc)) * 2048 + t0 + t4;
    *(us4*)dst = v;
  }
}

// ---------------- 256x256 8-phase bf16 MFMA GEMM, frag-prefetch pipelined ------
// 8 waves (2M x 4N), BK=64, LDS 128KB: 2 bufs x (A 32KB | B 32KB).
// kk-split phases per K-tile: P0(m0-3,kk0) P1(m4-7,kk0) P2(m0-3,kk1) P3(m4-7,kk1).
// Each phase issues NEXT phase's ds_reads before its MFMA cluster (reg dbuf:
// af0/af1 alternate by m-half, bf0=kk0 / bf1=kk1). Next-K-tile frags read at P3
// AFTER the vmcnt(4) gate. Every phase ends lgkmcnt(0) (free: reads issued one
// phase earlier) so no ds_read is in flight when later DMA overwrites the LDS.
// Gates: vmcnt(4) at ph4/ph8 only (never 0 in main loop).
template <int EPI>
__global__ __launch_bounds__(512, 2) void gemm8p(
    const unsigned short* __restrict__ A, int lda, long long sA,
    const unsigned short* __restrict__ B, int ldb, long long sB,
    void* __restrict__ Cv, int ldc, long long sC,
    const float* __restrict__ bias, float scale, int K, int NBX) {
  int bx, by;
  const int bz = blockIdx.z;
  if (EPI == 0) {
    int flat = blockIdx.x;
    int q = (int)gridDim.x >> 3;            // grid %8 == 0
    int swz = (flat & 7) * q + (flat >> 3); // XCD-contiguous remap
    bx = swz % NBX; by = swz / NBX;
  } else {
    bx = blockIdx.x; by = blockIdx.y;
    if (EPI == 1 && bx > by) return;
  }
  A += (size_t)bz * sA;
  B += (size_t)bz * sB;
  const int rowBase = by * 256;
  const int colBase = bx * 256;
  const int nk = (EPI == 2) ? (rowBase + 256) / 64 : K / 64;

  __shared__ __align__(16) unsigned char lds[131072];
  const int tid = threadIdx.x;
  const int lane = tid & 63;
  const int wid = tid >> 6;
  const int wr = wid >> 2;   // 0..1  (M half)
  const int wc = wid & 3;    // 0..3  (N quarter)
  const int l15 = lane & 15, l4 = lane >> 4, l7 = lane & 7;

  f32x4 acc[8][4] = {};
  bf16x8 af0[4], af1[4], bf0[4], bf1[4];

  // per-thread staging offsets (elements); lda==ldb at every call site.
  const unsigned short* Ab = A + (size_t)rowBase * lda;
  const unsigned short* Bb = B + (size_t)colBase * ldb;
  unsigned loff[2][2];
  unsigned lldso[2];
#pragma unroll
  for (int i = 0; i < 2; ++i) {
    int off = (i * 512 + tid) * 16;   // byte offset within 16KB half
    int r = off >> 7;                 // row 0..127 within half
    int sb = ((off >> 4) & 7) ^ (r & 7);
    lldso[i] = (unsigned)off;
#pragma unroll
    for (int h = 0; h < 2; ++h)
      loff[h][i] = (unsigned)((h * 128 + r) * lda + sb * 8);
  }

  auto STAGE = [&](int bufc, int isB, int half, const unsigned short* Gb, int koff) {
#pragma unroll
    for (int i = 0; i < 2; ++i)
      async16(Gb + (size_t)(loff[half][i] + (unsigned)koff),
              lds + bufc * 65536 + isB * 32768 + half * 16384 + lldso[i]);
  };
  auto RDA = [&](int bufc, int m, int kk) -> bf16x8 {
    int row = m * 16 + l15;                    // within this wave's 128-row half
    int blk = (kk * 4 + l4) ^ l7;
    return *(const bf16x8*)(lds + bufc * 65536 + wr * 16384 + row * 128 + blk * 16);
  };
  auto RDB = [&](int bufc, int n, int kk) -> bf16x8 {
    int row = (wc & 1) * 64 + n * 16 + l15;    // within B half (wc>>1)
    int blk = (kk * 4 + l4) ^ l7;
    return *(const bf16x8*)(lds + bufc * 65536 + 32768 + (wc >> 1) * 16384 +
                            row * 128 + blk * 16);
  };

#define RDAF(dst, BUF, MB, KK)                                                 \
  _Pragma("unroll") for (int mi = 0; mi < 4; ++mi) dst[mi] = RDA((BUF), (MB) + mi, (KK))
#define RDBF2(dst, BUF, N0, KK)                                                \
  do { dst[N0] = RDB((BUF), (N0), (KK)); dst[(N0) + 1] = RDB((BUF), (N0) + 1, (KK)); } while (0)
#define RDBF4(dst, BUF, KK)                                                    \
  _Pragma("unroll") for (int n = 0; n < 4; ++n) dst[n] = RDB((BUF), n, (KK))

// phase: [STAGE][bar][gate?][prefetch reads][16 MFMA][lgkm0][bar]
#define PH(MB, AFU, BFU, STG, GATE, RDS)                                       \
  do {                                                                         \
    STG;                                                                       \
    BARM();                                                                    \
    GATE;                                                                      \
    RDS;                                                                       \
    __builtin_amdgcn_s_setprio(1);                                             \
    _Pragma("unroll") for (int mi = 0; mi < 4; ++mi)                           \
    _Pragma("unroll") for (int n = 0; n < 4; ++n)                              \
        acc[(MB) + mi][n] = __builtin_amdgcn_mfma_f32_16x16x32_bf16(           \
            AFU[mi], BFU[n], acc[(MB) + mi][n], 0, 0, 0);                      \
    __builtin_amdgcn_s_setprio(0);                                             \
    LGKM0();                                                                   \
    BARM();                                                                    \
  } while (0)

  // prologue: tile0 (A,B)->buf0, tile1 B->buf1; gate leaves tile1's B in flight
  STAGE(0, 0, 0, Ab, 0);
  STAGE(0, 0, 1, Ab, 0);
  STAGE(0, 1, 0, Bb, 0);
  STAGE(0, 1, 1, Bb, 0);
  {
    int k1 = ((1 < nk - 1) ? 1 : (nk - 1)) * 64;
    STAGE(1, 1, 0, Bb, k1);
    STAGE(1, 1, 1, Bb, k1);
  }
  VMCNT4();
  BARM();
  RDAF(af0, 0, 0, 0);   // P0 operands: A m0-3 kk0
  RDBF4(bf0, 0, 0);     //              B kk0
  const int nt2 = nk >> 1;
  for (int it = 0; it < nt2; ++it) {
    int t = it * 2;
    int tA1 = t + 1 < nk - 1 ? t + 1 : nk - 1;
    int t2 = t + 2 < nk - 1 ? t + 2 : nk - 1;
    int t3 = t + 3 < nk - 1 ? t + 3 : nk - 1;
    int kA1 = tA1 * 64, k2 = t2 * 64, k3 = t3 * 64;
    // tile t from buf0
    PH(0, af0, bf0, STAGE(1, 0, 0, Ab, kA1), (void)0,
       { RDAF(af1, 0, 4, 0); RDBF2(bf1, 0, 0, 1); });
    PH(4, af1, bf0, STAGE(1, 0, 1, Ab, kA1), (void)0,
       { RDAF(af0, 0, 0, 1); RDBF2(bf1, 0, 2, 1); });
    PH(0, af0, bf1, STAGE(0, 1, 0, Bb, k2), (void)0,
       { RDAF(af1, 0, 4, 1); });
    PH(4, af1, bf1, STAGE(0, 1, 1, Bb, k2), VMCNT4(),
       { RDAF(af0, 1, 0, 0); RDBF4(bf0, 1, 0); });
    // tile t+1 from buf1
    PH(0, af0, bf0, STAGE(0, 0, 0, Ab, k2), (void)0,
       { RDAF(af1, 1, 4, 0); RDBF2(bf1, 1, 0, 1); });
    PH(4, af1, bf0, STAGE(0, 0, 1, Ab, k2), (void)0,
       { RDAF(af0, 1, 0, 1); RDBF2(bf1, 1, 2, 1); });
    PH(0, af0, bf1, STAGE(1, 1, 0, Bb, k3), (void)0,
       { RDAF(af1, 1, 4, 1); });
    PH(4, af1, bf1, STAGE(1, 1, 1, Bb, k3), VMCNT4(),
       { RDAF(af0, 0, 0, 0); RDBF4(bf0, 0, 0); });
  }
#undef PH
#undef RDAF
#undef RDBF2
#undef RDBF4

  const int cr = l4 * 4;
  if constexpr (EPI == 0) {
    unsigned short* C = (unsigned short*)Cv;
#pragma unroll
    for (int n = 0; n < 4; ++n) {
      int col = colBase + wc * 64 + n * 16 + l15;
      float bv = bias[col];
#pragma unroll
      for (int m = 0; m < 8; ++m) {
        int row = rowBase + wr * 128 + m * 16 + cr;
#pragma unroll
        for (int i = 0; i < 4; ++i)
          C[(size_t)(row + i) * ldc + col] = f2bf(acc[m][n][i] + bv);
      }
    }
  } else if constexpr (EPI == 1) {
    unsigned short* C = (unsigned short*)Cv + (size_t)bz * sC;
#pragma unroll
    for (int n = 0; n < 4; ++n) {
      int col = colBase + wc * 64 + n * 16 + l15;
#pragma unroll
      for (int m = 0; m < 8; ++m) {
        int row = rowBase + wr * 128 + m * 16 + cr;
#pragma unroll
        for (int i = 0; i < 4; ++i)
          C[(size_t)(row + i) * ldc + col] = f2bf(acc[m][n][i] * scale);
      }
    }
  } else {
    float* C = (float*)Cv + (size_t)bz * sC;
#pragma unroll
    for (int n = 0; n < 4; ++n) {
      int col = colBase + wc * 64 + n * 16 + l15;
#pragma unroll
      for (int m = 0; m < 8; ++m) {
        int row = rowBase + wr * 128 + m * 16 + cr;
#pragma unroll
        for (int i = 0; i < 4; ++i)
          C[(size_t)(row + i) * ldc + col] = acc[m][n][i];
      }
    }
  }
}

// ---------------- causal softmax over S rows (in place, bf16) ----------------
__global__ __launch_bounds__(256) void softmax_causal(unsigned short* __restrict__ S) {
  const int T = 2048;
  int t = blockIdx.x, b = blockIdx.y;
  unsigned short* row = S + ((size_t)b * T + t) * T;
  const int nv = t + 1;
  int tid = threadIdx.x;
  int lane = tid & 63, wid = tid >> 6;
  int s0 = tid * 8;
  us8 raw = *(const us8*)(row + s0);
  float v[8];
  float m = -3.0e38f;
#pragma unroll
  for (int j = 0; j < 8; ++j) {
    v[j] = bf2f(raw[j]);
    if (s0 + j < nv) m = fmaxf(m, v[j]);
  }
#pragma unroll
  for (int o = 32; o > 0; o >>= 1) m = fmaxf(m, __shfl_xor(m, o, 64));
  __shared__ float red[4];
  if (lane == 0) red[wid] = m;
  __syncthreads();
  m = fmaxf(fmaxf(red[0], red[1]), fmaxf(red[2], red[3]));
  __syncthreads();
  float sum = 0.f;
#pragma unroll
  for (int j = 0; j < 8; ++j) {
    float e = (s0 + j < nv) ? exp2f(v[j] - m) : 0.f;
    v[j] = e;
    sum += e;
  }
#pragma unroll
  for (int o = 32; o > 0; o >>= 1) sum += __shfl_xor(sum, o, 64);
  if (lane == 0) red[wid] = sum;
  __syncthreads();
  sum = red[0] + red[1] + red[2] + red[3];
  float inv = 1.0f / sum;
  us8 outv;
#pragma unroll
  for (int j = 0; j < 8; ++j) outv[j] = f2bf(v[j] * inv);
  *(us8*)(row + s0) = outv;
}

extern "C" void kernel_launch(void* const* d_in, const int* in_sizes, int n_in,
                              void* d_out, int out_size, void* d_ws, size_t ws_size,
                              hipStream_t stream) {
  const float* x = (const float*)d_in[0];      // [4,2048,1024]
  const float* W = (const float*)d_in[1];      // [3072,1024]
  const float* bias = (const float*)d_in[2];   // [3072]
  float* out = (float*)d_out;                  // [4,2048,1024]

  char* ws = (char*)d_ws;
  // layout: xbf 16MB (aliased by vT after gemm0) | wbf 6MB | kqv 48MB | S 32MB
  if (ws_size < 106954752u) return;
  unsigned short* xbf = (unsigned short*)(ws);
  unsigned short* vT = xbf;  // alias: xbf dead after gemm8p<0>
  unsigned short* wbf = (unsigned short*)(ws + 16777216);
  unsigned short* kqv = (unsigned short*)(ws + 23068672);
  unsigned short* S = (unsigned short*)(ws + 73400320);

  const float kSoftmaxScale = 1.4426950408889634f / 32.0f;  // log2(e)/sqrt(1024)

  cvt_bf16<<<8192, 256, 0, stream>>>(x, xbf, 2097152);
  cvt_bf16<<<3072, 256, 0, stream>>>(W, wbf, 786432);

  // kqv = x @ W^T + b   (M=8192, N=3072, K=1024) ; grid 32x12 = 384, XCD swizzle
  gemm8p<0><<<dim3(384, 1, 1), 512, 0, stream>>>(
      xbf, 1024, 0LL, wbf, 1024, 0LL, kqv, 3072, 0LL, bias, 1.0f, 1024, 12);

  transpose_v<<<dim3(32, 16, 4), 256, 0, stream>>>(kqv, vT);

  // S = (k @ q^T) * log2e/32 (bf16), causal blocks skipped
  gemm8p<1><<<dim3(8, 8, 4), 512, 0, stream>>>(
      kqv, 3072, 2048LL * 3072, kqv + 1024, 3072, 2048LL * 3072,
      S, 2048, 2048LL * 2048, nullptr, kSoftmaxScale, 1024, 0);

  softmax_causal<<<dim3(2048, 4), 256, 0, stream>>>(S);

  // out = P @ vT^T (fp32), K truncated at diagonal
  gemm8p<2><<<dim3(4, 8, 4), 512, 0, stream>>>(
      S, 2048, 2048LL * 2048, vT, 2048, 1024LL * 2048,
      out, 1024, 2048LL * 1024, nullptr, 1.0f, 2048, 0);
}